// Round 2
// baseline (234.562 us; speedup 1.0000x reference)
//
#include <hip/hip_runtime.h>

// AtomDistances: B=16, A=4096, N=128
//   out[b,a,n] = mask[b,a,n] ? || pos[b,nbr[b,a,n]] - pos[b,a] + co[b,a,n,:] @ cell[b] || : 0
//
// R1 finding: latency-bound (17% HBM, 9% VALU) on 12 divergent scalar gather
// loads per thread. R2: pad positions to float4 in d_ws so each gather is ONE
// aligned global_load_dwordx4 (4 divergent VMEM instrs/thread instead of 12).

#define A_DIM 4096
#define N_DIM 128
#define B_DIM 16

__global__ __launch_bounds__(256) void pad_positions_kernel(
    const float* __restrict__ pos,   // (B, A, 3)
    float4* __restrict__ pp)         // (B, A) padded
{
    const int i = blockIdx.x * blockDim.x + threadIdx.x;   // 0 .. B*A-1
    pp[i] = make_float4(pos[i * 3 + 0], pos[i * 3 + 1], pos[i * 3 + 2], 0.0f);
}

__global__ __launch_bounds__(256) void atom_distances_kernel(
    const float4* __restrict__ pp,           // (B, A) padded positions
    const int*    __restrict__ neighbors,    // (B, A, N) int32
    const float*  __restrict__ cell,         // (B, 3, 3)
    const float*  __restrict__ cell_offsets, // (B, A, N, 3)
    const int*    __restrict__ mask,         // (B, A, N) int32 (0/1)
    float* __restrict__ out)                 // (B, A, N)
{
    const int ELEMS_PER_BLOCK = 1024;                               // 256 thr * 4
    const int BLOCKS_PER_BATCH = (A_DIM * N_DIM) / ELEMS_PER_BLOCK; // 512

    const int b = blockIdx.x / BLOCKS_PER_BATCH;                    // block-uniform
    const int r = (blockIdx.x % BLOCKS_PER_BATCH) * ELEMS_PER_BLOCK + threadIdx.x * 4;
    const int a = r >> 7;                                           // r / N_DIM
    const int e = b * (A_DIM * N_DIM) + r;

    const float* cb = cell + b * 9;
    const float c00 = cb[0], c01 = cb[1], c02 = cb[2];
    const float c10 = cb[3], c11 = cb[4], c12 = cb[5];
    const float c20 = cb[6], c21 = cb[7], c22 = cb[8];

    const float4* pb4 = pp + b * A_DIM;
    const float4 ap = pb4[a];            // shared by 32 consecutive threads -> L1 broadcast

    // streaming loads, 16 B/lane, fully coalesced
    const int4 nb = *(const int4*)(neighbors + e);
    const int4 mk = *(const int4*)(mask + e);
    const float4* co = (const float4*)(cell_offsets + (size_t)e * 3);
    const float4 o0 = co[0];
    const float4 o1 = co[1];
    const float4 o2 = co[2];

    float cox[4], coy[4], coz[4];
    cox[0] = o0.x; coy[0] = o0.y; coz[0] = o0.z;
    cox[1] = o0.w; coy[1] = o1.x; coz[1] = o1.y;
    cox[2] = o1.z; coy[2] = o1.w; coz[2] = o2.x;
    cox[3] = o2.y; coy[3] = o2.z; coz[3] = o2.w;

    const int jj[4] = { nb.x, nb.y, nb.z, nb.w };
    const int mm[4] = { mk.x, mk.y, mk.z, mk.w };

    // gather: one aligned dwordx4 per neighbor (independent -> all in flight)
    float4 pj[4];
#pragma unroll
    for (int k = 0; k < 4; ++k) pj[k] = pb4[jj[k]];

    float res[4];
#pragma unroll
    for (int k = 0; k < 4; ++k) {
        const float dx = pj[k].x - ap.x + cox[k] * c00 + coy[k] * c10 + coz[k] * c20;
        const float dy = pj[k].y - ap.y + cox[k] * c01 + coy[k] * c11 + coz[k] * c21;
        const float dz = pj[k].z - ap.z + cox[k] * c02 + coy[k] * c12 + coz[k] * c22;
        const float d = sqrtf(dx * dx + dy * dy + dz * dz);
        res[k] = mm[k] ? d : 0.0f;
    }

    *(float4*)(out + e) = make_float4(res[0], res[1], res[2], res[3]);
}

// Fallback (R1 kernel): direct 3-float gather, used only if ws is too small.
__global__ __launch_bounds__(256) void atom_distances_direct_kernel(
    const float* __restrict__ positions,
    const int*   __restrict__ neighbors,
    const float* __restrict__ cell,
    const float* __restrict__ cell_offsets,
    const int*   __restrict__ mask,
    float* __restrict__ out)
{
    const int ELEMS_PER_BLOCK = 1024;
    const int BLOCKS_PER_BATCH = (A_DIM * N_DIM) / ELEMS_PER_BLOCK;

    const int b = blockIdx.x / BLOCKS_PER_BATCH;
    const int r = (blockIdx.x % BLOCKS_PER_BATCH) * ELEMS_PER_BLOCK + threadIdx.x * 4;
    const int a = r >> 7;
    const int e = b * (A_DIM * N_DIM) + r;

    const float* cb = cell + b * 9;
    const float c00 = cb[0], c01 = cb[1], c02 = cb[2];
    const float c10 = cb[3], c11 = cb[4], c12 = cb[5];
    const float c20 = cb[6], c21 = cb[7], c22 = cb[8];

    const float* pb = positions + b * (A_DIM * 3);
    const float ax = pb[a * 3 + 0], ay = pb[a * 3 + 1], az = pb[a * 3 + 2];

    const int4 nb = *(const int4*)(neighbors + e);
    const int4 mk = *(const int4*)(mask + e);
    const float4* co = (const float4*)(cell_offsets + (size_t)e * 3);
    const float4 o0 = co[0], o1 = co[1], o2 = co[2];

    float cox[4], coy[4], coz[4];
    cox[0] = o0.x; coy[0] = o0.y; coz[0] = o0.z;
    cox[1] = o0.w; coy[1] = o1.x; coz[1] = o1.y;
    cox[2] = o1.z; coy[2] = o1.w; coz[2] = o2.x;
    cox[3] = o2.y; coy[3] = o2.z; coz[3] = o2.w;

    const int jj[4] = { nb.x, nb.y, nb.z, nb.w };
    const int mm[4] = { mk.x, mk.y, mk.z, mk.w };

    float res[4];
#pragma unroll
    for (int k = 0; k < 4; ++k) {
        const float* pj = pb + jj[k] * 3;
        const float dx = pj[0] - ax + cox[k] * c00 + coy[k] * c10 + coz[k] * c20;
        const float dy = pj[1] - ay + cox[k] * c01 + coy[k] * c11 + coz[k] * c21;
        const float dz = pj[2] - az + cox[k] * c02 + coy[k] * c12 + coz[k] * c22;
        const float d = sqrtf(dx * dx + dy * dy + dz * dz);
        res[k] = mm[k] ? d : 0.0f;
    }
    *(float4*)(out + e) = make_float4(res[0], res[1], res[2], res[3]);
}

extern "C" void kernel_launch(void* const* d_in, const int* in_sizes, int n_in,
                              void* d_out, int out_size, void* d_ws, size_t ws_size,
                              hipStream_t stream) {
    const float* positions    = (const float*)d_in[0];
    const int*   neighbors    = (const int*)d_in[1];
    const float* cell         = (const float*)d_in[2];
    const float* cell_offsets = (const float*)d_in[3];
    const int*   mask         = (const int*)d_in[4];
    float* out = (float*)d_out;

    const int total  = out_size;          // B*A*N = 8,388,608
    const int blocks = total / 1024;      // 8192

    const size_t pad_bytes = (size_t)B_DIM * A_DIM * sizeof(float4);  // 1 MiB
    if (ws_size >= pad_bytes) {
        float4* pp = (float4*)d_ws;
        pad_positions_kernel<<<(B_DIM * A_DIM) / 256, 256, 0, stream>>>(positions, pp);
        atom_distances_kernel<<<blocks, 256, 0, stream>>>(
            pp, neighbors, cell, cell_offsets, mask, out);
    } else {
        atom_distances_direct_kernel<<<blocks, 256, 0, stream>>>(
            positions, neighbors, cell, cell_offsets, mask, out);
    }
}

// Round 3
// 210.995 us; speedup vs baseline: 1.1117x; 1.1117x over previous
//
#include <hip/hip_runtime.h>

// AtomDistances: B=16, A=4096, N=128
//   out[b,a,n] = mask[b,a,n] ? || pos[b,nbr[b,a,n]] - pos[b,a] + co[b,a,n,:] @ cell[b] || : 0
//
// R1/R2 finding: latency-bound on ~8.4M random position-gather L1 misses
// (MSHR-limited L2 queueing, ~85us). R3: stage the ENTIRE batch position
// window (4096 atoms = 64 KB float4) in LDS per block; gathers become
// ds_read_b128 and leave the global-memory path. Block = 1024 threads =
// 32 atoms x 128 neighbors; 2 blocks/CU -> full 32 waves/CU occupancy.

#define A_DIM 4096
#define N_DIM 128
#define B_DIM 16
#define ATOMS_PER_BLOCK 32           // 32*128 = 4096 elems = 1024 thr * 4
#define THREADS 1024

__global__ __launch_bounds__(THREADS) void atom_distances_lds_kernel(
    const float* __restrict__ positions,     // (B, A, 3)
    const int*   __restrict__ neighbors,     // (B, A, N) int32
    const float* __restrict__ cell,          // (B, 3, 3)
    const float* __restrict__ cell_offsets,  // (B, A, N, 3)
    const int*   __restrict__ mask,          // (B, A, N) int32 (0/1)
    float* __restrict__ out)                 // (B, A, N)
{
    __shared__ float4 lpos[A_DIM];           // 64 KB — whole batch window

    const int BLOCKS_PER_BATCH = A_DIM / ATOMS_PER_BLOCK;   // 128
    const int b  = blockIdx.x / BLOCKS_PER_BATCH;           // block-uniform
    const int a0 = (blockIdx.x % BLOCKS_PER_BATCH) * ATOMS_PER_BLOCK;

    // ---- stage all 4096 batch positions into LDS (coalesced-ish, 48 KB) ----
    const float* pb = positions + b * (A_DIM * 3);
    for (int j = threadIdx.x; j < A_DIM; j += THREADS) {
        lpos[j] = make_float4(pb[j * 3 + 0], pb[j * 3 + 1], pb[j * 3 + 2], 0.0f);
    }
    __syncthreads();

    // ---- per-thread element range: 4 consecutive n's ----
    const int r = threadIdx.x * 4;                          // 0..4095 in slab
    const int a = a0 + (r >> 7);                            // r / N_DIM
    const int e = (b * A_DIM + a0) * N_DIM + r;             // flat base

    const float* cb = cell + b * 9;                         // uniform -> sgpr
    const float c00 = cb[0], c01 = cb[1], c02 = cb[2];
    const float c10 = cb[3], c11 = cb[4], c12 = cb[5];
    const float c20 = cb[6], c21 = cb[7], c22 = cb[8];

    const float4 ap = lpos[a];       // same addr for 32 consecutive lanes -> LDS broadcast

    // streaming loads, 16 B/lane, fully coalesced
    const int4 nb = *(const int4*)(neighbors + e);
    const int4 mk = *(const int4*)(mask + e);
    const float4* co = (const float4*)(cell_offsets + (size_t)e * 3);
    const float4 o0 = co[0];
    const float4 o1 = co[1];
    const float4 o2 = co[2];

    float cox[4], coy[4], coz[4];
    cox[0] = o0.x; coy[0] = o0.y; coz[0] = o0.z;
    cox[1] = o0.w; coy[1] = o1.x; coz[1] = o1.y;
    cox[2] = o1.z; coy[2] = o1.w; coz[2] = o2.x;
    cox[3] = o2.y; coy[3] = o2.z; coz[3] = o2.w;

    const int jj[4] = { nb.x, nb.y, nb.z, nb.w };
    const int mm[4] = { mk.x, mk.y, mk.z, mk.w };

    // gather from LDS: ds_read_b128, random banks (~2-3x conflict cost, cheap)
    float4 pj[4];
#pragma unroll
    for (int k = 0; k < 4; ++k) pj[k] = lpos[jj[k]];

    float res[4];
#pragma unroll
    for (int k = 0; k < 4; ++k) {
        const float dx = pj[k].x - ap.x + cox[k] * c00 + coy[k] * c10 + coz[k] * c20;
        const float dy = pj[k].y - ap.y + cox[k] * c01 + coy[k] * c11 + coz[k] * c21;
        const float dz = pj[k].z - ap.z + cox[k] * c02 + coy[k] * c12 + coz[k] * c22;
        const float d = sqrtf(dx * dx + dy * dy + dz * dz);
        res[k] = mm[k] ? d : 0.0f;
    }

    *(float4*)(out + e) = make_float4(res[0], res[1], res[2], res[3]);
}

extern "C" void kernel_launch(void* const* d_in, const int* in_sizes, int n_in,
                              void* d_out, int out_size, void* d_ws, size_t ws_size,
                              hipStream_t stream) {
    const float* positions    = (const float*)d_in[0];
    const int*   neighbors    = (const int*)d_in[1];
    const float* cell         = (const float*)d_in[2];
    const float* cell_offsets = (const float*)d_in[3];
    const int*   mask         = (const int*)d_in[4];
    float* out = (float*)d_out;

    const int blocks = B_DIM * (A_DIM / ATOMS_PER_BLOCK);   // 16*128 = 2048
    atom_distances_lds_kernel<<<blocks, THREADS, 0, stream>>>(
        positions, neighbors, cell, cell_offsets, mask, out);
}

// Round 5
// 206.575 us; speedup vs baseline: 1.1355x; 1.0214x over previous
//
#include <hip/hip_runtime.h>

// AtomDistances: B=16, A=4096, N=128
//   out[b,a,n] = mask[b,a,n] ? || pos[b,nbr[b,a,n]] - pos[b,a] + co[b,a,n,:] @ cell[b] || : 0
//
// R3 finding: LDS gather is cheap (1.67M conflict cyc total); kernel was
// convoy-bound: stage 48KB -> barrier -> only 4 elems/thread -> die, x2048.
// R4/R5: 512 blocks (2/CU, full 32 waves/CU), stage batch window ONCE, then a
// barrier-free loop over 4 slabs (16 elems/thread). Nontemporal hints on the
// read-once streams and the store. (R5 = R4 with ext_vector_type instead of
// HIP_vector_type for the nontemporal builtins — compile fix.)

#define A_DIM 4096
#define N_DIM 128
#define B_DIM 16
#define THREADS 1024
#define BLOCKS_PER_BATCH 32                   // 512 blocks total
#define ATOMS_PER_BLOCK (A_DIM / BLOCKS_PER_BATCH)   // 128
#define SLAB_ATOMS 32                          // 32 atoms * 128 nbr = 4096 elems = THREADS*4
#define N_SLABS (ATOMS_PER_BLOCK / SLAB_ATOMS) // 4

typedef int   iv4 __attribute__((ext_vector_type(4)));
typedef float fv4 __attribute__((ext_vector_type(4)));

__global__ __launch_bounds__(THREADS) void atom_distances_kernel(
    const float* __restrict__ positions,     // (B, A, 3)
    const int*   __restrict__ neighbors,     // (B, A, N) int32
    const float* __restrict__ cell,          // (B, 3, 3)
    const float* __restrict__ cell_offsets,  // (B, A, N, 3)
    const int*   __restrict__ mask,          // (B, A, N) int32 (0/1)
    float* __restrict__ out)                 // (B, A, N)
{
    __shared__ fv4 lpos[A_DIM];              // 64 KB — whole batch window

    const int b      = blockIdx.x / BLOCKS_PER_BATCH;    // block-uniform
    const int a_base = (blockIdx.x % BLOCKS_PER_BATCH) * ATOMS_PER_BLOCK;

    // ---- stage all 4096 batch positions into LDS once (48 KB from L2/L3) ----
    const float* pb = positions + b * (A_DIM * 3);
    for (int j = threadIdx.x; j < A_DIM; j += THREADS) {
        fv4 p = { pb[j * 3 + 0], pb[j * 3 + 1], pb[j * 3 + 2], 0.0f };
        lpos[j] = p;
    }
    __syncthreads();                         // only barrier in the kernel

    const float* cb = cell + b * 9;          // uniform -> sgpr
    const float c00 = cb[0], c01 = cb[1], c02 = cb[2];
    const float c10 = cb[3], c11 = cb[4], c12 = cb[5];
    const float c20 = cb[6], c21 = cb[7], c22 = cb[8];

    const int r = threadIdx.x * 4;           // 0..4095 within a slab

    // ---- barrier-free streaming loop: 4 slabs x 4 elems/thread ----
    for (int s = 0; s < N_SLABS; ++s) {
        const int a0 = a_base + s * SLAB_ATOMS;
        const int a  = a0 + (r >> 7);                    // r / N_DIM
        const int e  = (b * A_DIM + a0) * N_DIM + r;     // flat element base

        const fv4 ap = lpos[a];   // same addr across 32 lanes -> LDS broadcast

        // streaming loads, 16 B/lane, fully coalesced, read-once -> nontemporal
        const iv4 nb = __builtin_nontemporal_load((const iv4*)(neighbors + e));
        const iv4 mk = __builtin_nontemporal_load((const iv4*)(mask + e));
        const fv4* co = (const fv4*)(cell_offsets + (size_t)e * 3);
        const fv4 o0 = __builtin_nontemporal_load(co + 0);
        const fv4 o1 = __builtin_nontemporal_load(co + 1);
        const fv4 o2 = __builtin_nontemporal_load(co + 2);

        float cox[4], coy[4], coz[4];
        cox[0] = o0.x; coy[0] = o0.y; coz[0] = o0.z;
        cox[1] = o0.w; coy[1] = o1.x; coz[1] = o1.y;
        cox[2] = o1.z; coy[2] = o1.w; coz[2] = o2.x;
        cox[3] = o2.y; coy[3] = o2.z; coz[3] = o2.w;

        const int jj[4] = { nb.x, nb.y, nb.z, nb.w };
        const int mm[4] = { mk.x, mk.y, mk.z, mk.w };

        // gather from LDS: ds_read_b128 (random banks — measured cheap)
        fv4 pj[4];
#pragma unroll
        for (int k = 0; k < 4; ++k) pj[k] = lpos[jj[k]];

        fv4 res;
#pragma unroll
        for (int k = 0; k < 4; ++k) {
            const float dx = pj[k].x - ap.x + cox[k] * c00 + coy[k] * c10 + coz[k] * c20;
            const float dy = pj[k].y - ap.y + cox[k] * c01 + coy[k] * c11 + coz[k] * c21;
            const float dz = pj[k].z - ap.z + cox[k] * c02 + coy[k] * c12 + coz[k] * c22;
            const float d = sqrtf(dx * dx + dy * dy + dz * dz);
            res[k] = mm[k] ? d : 0.0f;
        }

        __builtin_nontemporal_store(res, (fv4*)(out + e));
    }
}

extern "C" void kernel_launch(void* const* d_in, const int* in_sizes, int n_in,
                              void* d_out, int out_size, void* d_ws, size_t ws_size,
                              hipStream_t stream) {
    const float* positions    = (const float*)d_in[0];
    const int*   neighbors    = (const int*)d_in[1];
    const float* cell         = (const float*)d_in[2];
    const float* cell_offsets = (const float*)d_in[3];
    const int*   mask         = (const int*)d_in[4];
    float* out = (float*)d_out;

    const int blocks = B_DIM * BLOCKS_PER_BATCH;   // 512
    atom_distances_kernel<<<blocks, THREADS, 0, stream>>>(
        positions, neighbors, cell, cell_offsets, mask, out);
}

// Round 6
// 205.421 us; speedup vs baseline: 1.1419x; 1.0056x over previous
//
#include <hip/hip_runtime.h>

// AtomDistances: B=16, A=4096, N=128
//   out[b,a,n] = mask[b,a,n] ? || pos[b,nbr[b,a,n]] - pos[b,a] + co[b,a,n,:] @ cell[b] || : 0
//
// R3: LDS-staged positions (gathers leave global path)  89 -> 70.7 us
// R4/R5: 512 blocks, stage once, barrier-free 4-slab loop -> <58.6 us
// R6: 2-stage software pipeline (prefetch slab s+1 globals under slab s
//     gather+math) + single-instruction v_sqrt_f32 via __builtin_amdgcn_sqrtf.

#define A_DIM 4096
#define N_DIM 128
#define B_DIM 16
#define THREADS 1024
#define BLOCKS_PER_BATCH 32                          // 512 blocks total
#define ATOMS_PER_BLOCK (A_DIM / BLOCKS_PER_BATCH)   // 128
#define SLAB_ATOMS 32                                // 32 atoms * 128 nbr = 4096 = THREADS*4
#define N_SLABS (ATOMS_PER_BLOCK / SLAB_ATOMS)       // 4

typedef int   iv4 __attribute__((ext_vector_type(4)));
typedef float fv4 __attribute__((ext_vector_type(4)));

__global__ __launch_bounds__(THREADS) void atom_distances_kernel(
    const float* __restrict__ positions,     // (B, A, 3)
    const int*   __restrict__ neighbors,     // (B, A, N) int32
    const float* __restrict__ cell,          // (B, 3, 3)
    const float* __restrict__ cell_offsets,  // (B, A, N, 3)
    const int*   __restrict__ mask,          // (B, A, N) int32 (0/1)
    float* __restrict__ out)                 // (B, A, N)
{
    __shared__ fv4 lpos[A_DIM];              // 64 KB — whole batch window

    const int b      = blockIdx.x / BLOCKS_PER_BATCH;    // block-uniform
    const int a_base = (blockIdx.x % BLOCKS_PER_BATCH) * ATOMS_PER_BLOCK;

    // ---- stage all 4096 batch positions into LDS once (48 KB, L2/L3-hit) ----
    const float* pb = positions + b * (A_DIM * 3);
    for (int j = threadIdx.x; j < A_DIM; j += THREADS) {
        fv4 p = { pb[j * 3 + 0], pb[j * 3 + 1], pb[j * 3 + 2], 0.0f };
        lpos[j] = p;
    }
    __syncthreads();                         // only barrier in the kernel

    const float* cb = cell + b * 9;          // uniform -> sgpr
    const float c00 = cb[0], c01 = cb[1], c02 = cb[2];
    const float c10 = cb[3], c11 = cb[4], c12 = cb[5];
    const float c20 = cb[6], c21 = cb[7], c22 = cb[8];

    const int r = threadIdx.x * 4;           // 0..4095 within a slab

    // ---- 2-stage software-pipelined streaming loop ----
    // prologue: prefetch slab 0
    int e_cur = (b * A_DIM + a_base) * N_DIM + r;
    iv4 nb = __builtin_nontemporal_load((const iv4*)(neighbors + e_cur));
    iv4 mk = __builtin_nontemporal_load((const iv4*)(mask + e_cur));
    const fv4* co = (const fv4*)(cell_offsets + (size_t)e_cur * 3);
    fv4 o0 = __builtin_nontemporal_load(co + 0);
    fv4 o1 = __builtin_nontemporal_load(co + 1);
    fv4 o2 = __builtin_nontemporal_load(co + 2);

#pragma unroll
    for (int s = 0; s < N_SLABS; ++s) {
        const int a0 = a_base + s * SLAB_ATOMS;
        const int a  = a0 + (r >> 7);
        const int e  = e_cur;

        // start LDS gathers for current slab (depends only on nb)
        const int jj[4] = { nb.x, nb.y, nb.z, nb.w };
        fv4 pj[4];
#pragma unroll
        for (int k = 0; k < 4; ++k) pj[k] = lpos[jj[k]];
        const fv4 ap = lpos[a];              // broadcast across 32 lanes

        const int mm[4] = { mk.x, mk.y, mk.z, mk.w };
        const fv4 po0 = o0, po1 = o1, po2 = o2;

        // prefetch next slab's global streams under this slab's math
        if (s + 1 < N_SLABS) {
            e_cur += SLAB_ATOMS * N_DIM;
            nb = __builtin_nontemporal_load((const iv4*)(neighbors + e_cur));
            mk = __builtin_nontemporal_load((const iv4*)(mask + e_cur));
            const fv4* con = (const fv4*)(cell_offsets + (size_t)e_cur * 3);
            o0 = __builtin_nontemporal_load(con + 0);
            o1 = __builtin_nontemporal_load(con + 1);
            o2 = __builtin_nontemporal_load(con + 2);
        }

        float cox[4], coy[4], coz[4];
        cox[0] = po0.x; coy[0] = po0.y; coz[0] = po0.z;
        cox[1] = po0.w; coy[1] = po1.x; coz[1] = po1.y;
        cox[2] = po1.z; coy[2] = po1.w; coz[2] = po2.x;
        cox[3] = po2.y; coy[3] = po2.z; coz[3] = po2.w;

        fv4 res;
#pragma unroll
        for (int k = 0; k < 4; ++k) {
            const float dx = pj[k].x - ap.x + cox[k] * c00 + coy[k] * c10 + coz[k] * c20;
            const float dy = pj[k].y - ap.y + cox[k] * c01 + coy[k] * c11 + coz[k] * c21;
            const float dz = pj[k].z - ap.z + cox[k] * c02 + coy[k] * c12 + coz[k] * c22;
            const float d = __builtin_amdgcn_sqrtf(dx * dx + dy * dy + dz * dz);
            res[k] = mm[k] ? d : 0.0f;
        }

        __builtin_nontemporal_store(res, (fv4*)(out + e));
    }
}

extern "C" void kernel_launch(void* const* d_in, const int* in_sizes, int n_in,
                              void* d_out, int out_size, void* d_ws, size_t ws_size,
                              hipStream_t stream) {
    const float* positions    = (const float*)d_in[0];
    const int*   neighbors    = (const int*)d_in[1];
    const float* cell         = (const float*)d_in[2];
    const float* cell_offsets = (const float*)d_in[3];
    const int*   mask         = (const int*)d_in[4];
    float* out = (float*)d_out;

    const int blocks = B_DIM * BLOCKS_PER_BATCH;   // 512
    atom_distances_kernel<<<blocks, THREADS, 0, stream>>>(
        positions, neighbors, cell, cell_offsets, mask, out);
}

// Round 7
// 204.368 us; speedup vs baseline: 1.1477x; 1.0052x over previous
//
#include <hip/hip_runtime.h>

// AtomDistances: B=16, A=4096, N=128
//   out[b,a,n] = mask[b,a,n] ? || pos[b,nbr[b,a,n]] - pos[b,a] + co[b,a,n,:] @ cell[b] || : 0
//
// R3: LDS-staged positions  89 -> 70.7 us
// R4/R5: 512 blocks, stage once, 4-slab loop -> <58.6 us
// R6: explicit prefetch pipeline -> neutral. Theory: full unroll + prefetch
//     pushed VGPR past 64 -> only 1 of 2 blocks resident -> 16 waves/CU.
// R7: rolled loop (one slab live), __launch_bounds__(1024,8) to force
//     VGPR<=64 so BOTH blocks are resident (32 waves/CU). TLP > pipelining.

#define A_DIM 4096
#define N_DIM 128
#define B_DIM 16
#define THREADS 1024
#define BLOCKS_PER_BATCH 32                          // 512 blocks total
#define ATOMS_PER_BLOCK (A_DIM / BLOCKS_PER_BATCH)   // 128
#define SLAB_ATOMS 32                                // 32 atoms * 128 nbr = 4096 = THREADS*4
#define N_SLABS (ATOMS_PER_BLOCK / SLAB_ATOMS)       // 4

typedef int   iv4 __attribute__((ext_vector_type(4)));
typedef float fv4 __attribute__((ext_vector_type(4)));

__global__ __launch_bounds__(THREADS, 8) void atom_distances_kernel(
    const float* __restrict__ positions,     // (B, A, 3)
    const int*   __restrict__ neighbors,     // (B, A, N) int32
    const float* __restrict__ cell,          // (B, 3, 3)
    const float* __restrict__ cell_offsets,  // (B, A, N, 3)
    const int*   __restrict__ mask,          // (B, A, N) int32 (0/1)
    float* __restrict__ out)                 // (B, A, N)
{
    __shared__ fv4 lpos[A_DIM];              // 64 KB — whole batch window

    const int b      = blockIdx.x / BLOCKS_PER_BATCH;    // block-uniform
    const int a_base = (blockIdx.x % BLOCKS_PER_BATCH) * ATOMS_PER_BLOCK;

    // ---- stage all 4096 batch positions into LDS once (48 KB, L2/L3-hit) ----
    const float* pb = positions + b * (A_DIM * 3);
    for (int j = threadIdx.x; j < A_DIM; j += THREADS) {
        fv4 p = { pb[j * 3 + 0], pb[j * 3 + 1], pb[j * 3 + 2], 0.0f };
        lpos[j] = p;
    }
    __syncthreads();                         // only barrier in the kernel

    const float* cb = cell + b * 9;          // uniform -> sgpr
    const float c00 = cb[0], c01 = cb[1], c02 = cb[2];
    const float c10 = cb[3], c11 = cb[4], c12 = cb[5];
    const float c20 = cb[6], c21 = cb[7], c22 = cb[8];

    const int r = threadIdx.x * 4;           // 0..4095 within a slab

    // ---- rolled streaming loop: minimal live state, 32 waves/CU hide latency
#pragma unroll 1
    for (int s = 0; s < N_SLABS; ++s) {
        const int a0 = a_base + s * SLAB_ATOMS;
        const int a  = a0 + (r >> 7);                    // r / N_DIM
        const int e  = (b * A_DIM + a0) * N_DIM + r;     // flat element base

        const iv4 nb = __builtin_nontemporal_load((const iv4*)(neighbors + e));
        const iv4 mk = __builtin_nontemporal_load((const iv4*)(mask + e));
        const fv4* co = (const fv4*)(cell_offsets + (size_t)e * 3);
        const fv4 o0 = __builtin_nontemporal_load(co + 0);
        const fv4 o1 = __builtin_nontemporal_load(co + 1);
        const fv4 o2 = __builtin_nontemporal_load(co + 2);

        const fv4 ap = lpos[a];              // LDS broadcast across 32 lanes

        const int jj[4] = { nb.x, nb.y, nb.z, nb.w };
        fv4 pj[4];
#pragma unroll
        for (int k = 0; k < 4; ++k) pj[k] = lpos[jj[k]];   // ds_read_b128 gather

        const int mm[4] = { mk.x, mk.y, mk.z, mk.w };

        float cox[4], coy[4], coz[4];
        cox[0] = o0.x; coy[0] = o0.y; coz[0] = o0.z;
        cox[1] = o0.w; coy[1] = o1.x; coz[1] = o1.y;
        cox[2] = o1.z; coy[2] = o1.w; coz[2] = o2.x;
        cox[3] = o2.y; coy[3] = o2.z; coz[3] = o2.w;

        fv4 res;
#pragma unroll
        for (int k = 0; k < 4; ++k) {
            const float dx = pj[k].x - ap.x + cox[k] * c00 + coy[k] * c10 + coz[k] * c20;
            const float dy = pj[k].y - ap.y + cox[k] * c01 + coy[k] * c11 + coz[k] * c21;
            const float dz = pj[k].z - ap.z + cox[k] * c02 + coy[k] * c12 + coz[k] * c22;
            const float d = __builtin_amdgcn_sqrtf(dx * dx + dy * dy + dz * dz);
            res[k] = mm[k] ? d : 0.0f;
        }

        __builtin_nontemporal_store(res, (fv4*)(out + e));
    }
}

extern "C" void kernel_launch(void* const* d_in, const int* in_sizes, int n_in,
                              void* d_out, int out_size, void* d_ws, size_t ws_size,
                              hipStream_t stream) {
    const float* positions    = (const float*)d_in[0];
    const int*   neighbors    = (const int*)d_in[1];
    const float* cell         = (const float*)d_in[2];
    const float* cell_offsets = (const float*)d_in[3];
    const int*   mask         = (const int*)d_in[4];
    float* out = (float*)d_out;

    const int blocks = B_DIM * BLOCKS_PER_BATCH;   // 512
    atom_distances_kernel<<<blocks, THREADS, 0, stream>>>(
        positions, neighbors, cell, cell_offsets, mask, out);
}